// Round 2
// baseline (1620.779 us; speedup 1.0000x reference)
//
#include <hip/hip_runtime.h>
#include <hip/hip_bf16.h>
#include <math.h>

typedef __bf16 bf16;
typedef __bf16 v8bf __attribute__((ext_vector_type(8)));
typedef float v4f __attribute__((ext_vector_type(4)));

#define B_   4
#define S_   2048
#define E_   1024
#define CS_  16
#define NC_  8
#define H_   16
#define D_   1040
#define DH_  65
#define DFF_ 4096
#define M_   8192

__device__ __forceinline__ v4f mfma16(v8bf a, v8bf b, v4f c) {
    return __builtin_amdgcn_mfma_f32_16x16x32_bf16(a, b, c, 0, 0, 0);
}

// ---------------- f32 -> bf16 weight conversion ----------------
__global__ __launch_bounds__(256) void k_cvt(const float* __restrict__ src,
                                             bf16* __restrict__ dst, int n) {
    int i = (blockIdx.x * 256 + threadIdx.x) * 4;
    if (i + 4 <= n) {
        float4 v = *(const float4*)(src + i);
        bf16 o[4] = {(bf16)v.x, (bf16)v.y, (bf16)v.z, (bf16)v.w};
        *(ushort4*)(dst + i) = *(const ushort4*)o;
    }
}

// ---------------- zero fill (uint4 granules) ----------------
__global__ __launch_bounds__(256) void k_zero(uint4* __restrict__ p, int n4) {
    int i = blockIdx.x * 256 + threadIdx.x;
    uint4 z = {0u, 0u, 0u, 0u};
    if (i < n4) p[i] = z;
}

// ---------------- LayerNorm(x f32) + concat cond -> xc (M x D) bf16 ----------------
__global__ __launch_bounds__(256) void k_ln_concat(
    const float* __restrict__ x, const float* __restrict__ cond,
    const float* __restrict__ g, const float* __restrict__ bn,
    bf16* __restrict__ xc)
{
    int row = blockIdx.x;
    int t = threadIdx.x;
    const float* xr = x + (size_t)row * E_;
    float4 v = *(const float4*)(xr + t * 4);
    float s = v.x + v.y + v.z + v.w;
    float ss = v.x * v.x + v.y * v.y + v.z * v.z + v.w * v.w;
#pragma unroll
    for (int off = 32; off; off >>= 1) {
        s  += __shfl_down(s, off);
        ss += __shfl_down(ss, off);
    }
    __shared__ float red[8];
    int wid = t >> 6;
    if ((t & 63) == 0) { red[wid] = s; red[4 + wid] = ss; }
    __syncthreads();
    float stot  = red[0] + red[1] + red[2] + red[3];
    float sstot = red[4] + red[5] + red[6] + red[7];
    float mean = stot * (1.0f / E_);
    float var  = sstot * (1.0f / E_) - mean * mean;
    float rs = rsqrtf(var + 1e-5f);
    bf16* xcr = xc + (size_t)row * D_;
    float vv[4] = {v.x, v.y, v.z, v.w};
#pragma unroll
    for (int j = 0; j < 4; ++j) {
        int i = t * 4 + j;
        xcr[i] = (bf16)(((vv[j] - mean) * rs) * g[i] + bn[i]);
    }
    if (t < CS_) xcr[E_ + t] = (bf16)cond[(size_t)row * CS_ + t];
}

// ---------------- GEMM: C[m,n] = sum_k A[m,k]*B[n,k] + epilogue ----------------
#define EP_Q   0
#define EP_V   1
#define EP_K   2
#define EP_O   3
#define EP_FF1 4
#define EP_FF2 5

template<int EP>
__global__ __launch_bounds__(256) void k_gemm(
    const bf16* __restrict__ A, const bf16* __restrict__ Bm,
    const float* __restrict__ bias,
    int M, int N, int K, int lda, int ldb,
    bf16* __restrict__ Cb, float* __restrict__ Cf, int ldc,
    const bf16* __restrict__ res, int ldres,
    const float* __restrict__ condw, const float* __restrict__ bkp)
{
    __shared__ bf16 As[128][32];
    __shared__ bf16 Bs[128][32];
    int t = threadIdx.x;
    int n0 = blockIdx.x * 128, m0 = blockIdx.y * 128;
    int lane = t & 63, w = t >> 6;
    int wm = (w >> 1) * 64, wn = (w & 1) * 64;
    int lr = lane & 15, lq = lane >> 4;

    v4f acc[4][4];
    v4f vzero = {0.f, 0.f, 0.f, 0.f};
#pragma unroll
    for (int mt = 0; mt < 4; ++mt)
#pragma unroll
        for (int nt = 0; nt < 4; ++nt) acc[mt][nt] = vzero;

    const int KT = (K + 31) >> 5;
    const int CLOOP = (EP == EP_K) ? NC_ : 1;

    for (int c = 0; c < CLOOP; ++c) {
        const bf16* Bc = (EP == EP_K) ? (Bm + (size_t)c * D_ * D_) : Bm;
        for (int kb = 0; kb < KT; ++kb) {
            int k0 = kb << 5;
#pragma unroll
            for (int i = 0; i < 2; ++i) {
                int idx = t + i * 256;
                int row = idx >> 2, seg = idx & 3;
                int gk = k0 + seg * 8;
                uint4 val = {0u, 0u, 0u, 0u};
                if (gk + 8 <= K) val = *(const uint4*)(A + (size_t)(m0 + row) * lda + gk);
                if constexpr (EP == EP_K) {
                    float wv = condw[(size_t)(m0 + row) * CS_ + c];
                    union { uint4 u; bf16 h[8]; } u8;
                    u8.u = val;
#pragma unroll
                    for (int j = 0; j < 8; ++j) u8.h[j] = (bf16)((float)u8.h[j] * wv);
                    val = u8.u;
                }
                *(uint4*)(&As[row][seg * 8]) = val;

                int gn = n0 + row;
                uint4 bv = {0u, 0u, 0u, 0u};
                if (gn < N && gk + 8 <= K) bv = *(const uint4*)(Bc + (size_t)gn * ldb + gk);
                *(uint4*)(&Bs[row][seg * 8]) = bv;
            }
            __syncthreads();
            v8bf af[4], bfr[4];
#pragma unroll
            for (int mt = 0; mt < 4; ++mt) af[mt]  = *(const v8bf*)(&As[wm + mt * 16 + lr][lq * 8]);
#pragma unroll
            for (int nt = 0; nt < 4; ++nt) bfr[nt] = *(const v8bf*)(&Bs[wn + nt * 16 + lr][lq * 8]);
#pragma unroll
            for (int mt = 0; mt < 4; ++mt)
#pragma unroll
                for (int nt = 0; nt < 4; ++nt)
                    acc[mt][nt] = mfma16(af[mt], bfr[nt], acc[mt][nt]);
            __syncthreads();
        }
    }

    // element (mt,nt,reg): row = m0+wm+mt*16+lq*4+reg, col = n0+wn+nt*16+lr
#pragma unroll
    for (int mt = 0; mt < 4; ++mt) {
#pragma unroll
        for (int reg = 0; reg < 4; ++reg) {
            int grow = m0 + wm + mt * 16 + lq * 4 + reg;
#pragma unroll
            for (int nt = 0; nt < 4; ++nt) {
                int gcol = n0 + wn + nt * 16 + lr;
                if (gcol < N) {
                    float vacc = acc[mt][nt][reg];
                    if constexpr (EP == EP_Q || EP == EP_K) {
                        float o;
                        if constexpr (EP == EP_Q) {
                            o = (vacc + bias[gcol]) * 0.1240347346f; // 1/sqrt(65)
                        } else {
                            float bb = 0.f;
#pragma unroll
                            for (int c = 0; c < NC_; ++c)
                                bb += condw[(size_t)grow * CS_ + c] * bkp[(size_t)c * D_ + gcol];
                            o = vacc + bb;
                        }
                        int h = gcol / 65, d = gcol - h * 65;
                        int b = grow >> 11, s = grow & 2047;
                        Cb[(((size_t)(b * 16 + h)) * S_ + s) * 96 + d] = (bf16)o;
                    } else if constexpr (EP == EP_V) {
                        Cb[(size_t)grow * ldc + gcol] = (bf16)(vacc + bias[gcol]);
                    } else if constexpr (EP == EP_O) {
                        float o = vacc + bias[gcol] + (float)res[(size_t)grow * ldres + gcol];
                        Cb[(size_t)grow * ldc + gcol] = (bf16)o;
                    } else if constexpr (EP == EP_FF1) {
                        float o = vacc + bias[gcol];
                        Cb[(size_t)grow * ldc + gcol] = (bf16)fmaxf(o, 0.f);
                    } else { // EP_FF2
                        Cf[(size_t)grow * ldc + gcol] =
                            vacc + bias[gcol] + (float)res[(size_t)grow * ldres + gcol];
                    }
                }
            }
        }
    }
}

// ---------------- transpose v (M x D bf16) into vt [bh][d(80)][s] ----------------
__global__ __launch_bounds__(256) void k_transpose_v(
    const bf16* __restrict__ v, bf16* __restrict__ vt)
{
    int bh = blockIdx.y, s0 = blockIdx.x * 64;
    int b = bh >> 4, h = bh & 15;
    __shared__ bf16 tile[80][65];
#pragma unroll
    for (int i = 0; i < 20; ++i) { // 80*64/256
        int idx = threadIdx.x + i * 256;
        int d = idx % 80, sl = idx / 80;
        bf16 val = (bf16)0.f;
        if (d < DH_) val = v[((size_t)b * S_ + s0 + sl) * D_ + h * DH_ + d];
        tile[d][sl] = val;
    }
    __syncthreads();
#pragma unroll
    for (int i = 0; i < 20; ++i) {
        int idx = threadIdx.x + i * 256;
        int sl = idx % 64, d = idx / 64;
        vt[((size_t)bh * 80 + d) * S_ + s0 + sl] = tile[d][sl];
    }
}

// ---------------- flash attention: qp,kp [bh][s][96], vt [bh][80][s] -> o (M x D) bf16 ----------------
__global__ __launch_bounds__(256) void k_attn(
    const bf16* __restrict__ qp, const bf16* __restrict__ kp,
    const bf16* __restrict__ vt, bf16* __restrict__ o)
{
    int bh = blockIdx.y;
    int s0 = blockIdx.x * 64;
    int b = bh >> 4, h = bh & 15;
    int t = threadIdx.x, lane = t & 63, w = t >> 6;
    int lr = lane & 15, lq = lane >> 4;

    __shared__ bf16 Qs[64][96];
    __shared__ bf16 Ks[64][96];
    __shared__ bf16 Vs[80][64];
    __shared__ bf16 Ps[4][16][64];

    const bf16* qbase = qp + ((size_t)bh * S_ + s0) * 96;
#pragma unroll
    for (int i = 0; i < 3; ++i) { // 64 rows * 12 segs
        int idx = t + i * 256;
        int row = idx / 12, seg = idx % 12;
        *(uint4*)(&Qs[row][seg * 8]) = *(const uint4*)(qbase + (size_t)row * 96 + seg * 8);
    }

    float m_r[4], l_r[4];
    v4f o_acc[5];
    v4f vzero = {0.f, 0.f, 0.f, 0.f};
#pragma unroll
    for (int r = 0; r < 4; ++r) { m_r[r] = -1e30f; l_r[r] = 0.f; }
#pragma unroll
    for (int nt = 0; nt < 5; ++nt) o_acc[nt] = vzero;

    for (int kb = 0; kb < S_ / 64; ++kb) {
        const bf16* kbase = kp + ((size_t)bh * S_ + kb * 64) * 96;
#pragma unroll
        for (int i = 0; i < 3; ++i) {
            int idx = t + i * 256;
            int row = idx / 12, seg = idx % 12;
            *(uint4*)(&Ks[row][seg * 8]) = *(const uint4*)(kbase + (size_t)row * 96 + seg * 8);
        }
#pragma unroll
        for (int i = 0; i < 3; ++i) { // 80 rows * 8 segs = 640
            int idx = t + i * 256;
            if (idx < 640) {
                int d = idx >> 3, seg = idx & 7;
                *(uint4*)(&Vs[d][seg * 8]) =
                    *(const uint4*)(vt + ((size_t)bh * 80 + d) * S_ + kb * 64 + seg * 8);
            }
        }
        __syncthreads();

        v4f sacc[4];
#pragma unroll
        for (int nt = 0; nt < 4; ++nt) sacc[nt] = vzero;
#pragma unroll
        for (int ks = 0; ks < 3; ++ks) {
            v8bf aq = *(const v8bf*)(&Qs[w * 16 + lr][ks * 32 + lq * 8]);
#pragma unroll
            for (int nt = 0; nt < 4; ++nt) {
                v8bf bk2 = *(const v8bf*)(&Ks[nt * 16 + lr][ks * 32 + lq * 8]);
                sacc[nt] = mfma16(aq, bk2, sacc[nt]);
            }
        }

        float alpha[4];
#pragma unroll
        for (int r = 0; r < 4; ++r) {
            float mx = fmaxf(fmaxf(sacc[0][r], sacc[1][r]), fmaxf(sacc[2][r], sacc[3][r]));
#pragma unroll
            for (int off = 1; off < 16; off <<= 1) mx = fmaxf(mx, __shfl_xor(mx, off));
            float mnew = fmaxf(m_r[r], mx);
            alpha[r] = __expf(m_r[r] - mnew);
            float ps = 0.f;
#pragma unroll
            for (int nt = 0; nt < 4; ++nt) {
                float p = __expf(sacc[nt][r] - mnew);
                sacc[nt][r] = p;
                ps += p;
            }
#pragma unroll
            for (int off = 1; off < 16; off <<= 1) ps += __shfl_xor(ps, off);
            l_r[r] = l_r[r] * alpha[r] + ps;
            m_r[r] = mnew;
        }

#pragma unroll
        for (int nt = 0; nt < 4; ++nt)
#pragma unroll
            for (int r = 0; r < 4; ++r)
                Ps[w][lq * 4 + r][nt * 16 + lr] = (bf16)sacc[nt][r];
        asm volatile("s_waitcnt lgkmcnt(0)" ::: "memory");

#pragma unroll
        for (int nt = 0; nt < 5; ++nt)
#pragma unroll
            for (int r = 0; r < 4; ++r) o_acc[nt][r] *= alpha[r];

#pragma unroll
        for (int kt = 0; kt < 2; ++kt) {
            v8bf ap = *(const v8bf*)(&Ps[w][lr][kt * 32 + lq * 8]);
#pragma unroll
            for (int nt = 0; nt < 5; ++nt) {
                v8bf bv2 = *(const v8bf*)(&Vs[nt * 16 + lr][kt * 32 + lq * 8]);
                o_acc[nt] = mfma16(ap, bv2, o_acc[nt]);
            }
        }
        __syncthreads();
    }

    int token = b * S_ + s0 + w * 16 + lq * 4;
#pragma unroll
    for (int nt = 0; nt < 5; ++nt) {
        int d = nt * 16 + lr;
        if (d < DH_) {
#pragma unroll
            for (int r = 0; r < 4; ++r)
                o[(size_t)(token + r) * D_ + h * DH_ + d] = (bf16)(o_acc[nt][r] / l_r[r]);
        }
    }
}

// ---------------- final LayerNorm on z (f32) -> out f32 ----------------
__global__ __launch_bounds__(256) void k_ln_out(
    const float* __restrict__ z, const float* __restrict__ g,
    const float* __restrict__ bn, float* __restrict__ out)
{
    int row = blockIdx.x;
    int t = threadIdx.x;
    const float* zr = z + (size_t)row * E_;
    float4 v = *(const float4*)(zr + t * 4);
    float s = v.x + v.y + v.z + v.w;
    float ss = v.x * v.x + v.y * v.y + v.z * v.z + v.w * v.w;
#pragma unroll
    for (int off = 32; off; off >>= 1) {
        s  += __shfl_down(s, off);
        ss += __shfl_down(ss, off);
    }
    __shared__ float red[8];
    int wid = t >> 6;
    if ((t & 63) == 0) { red[wid] = s; red[4 + wid] = ss; }
    __syncthreads();
    float stot  = red[0] + red[1] + red[2] + red[3];
    float sstot = red[4] + red[5] + red[6] + red[7];
    float mean = stot * (1.0f / E_);
    float var  = sstot * (1.0f / E_) - mean * mean;
    float rs = rsqrtf(var + 1e-5f);
    float* outr = out + (size_t)row * E_;
    float vv[4] = {v.x, v.y, v.z, v.w};
#pragma unroll
    for (int j = 0; j < 4; ++j) {
        int i = t * 4 + j;
        outr[i] = ((vv[j] - mean) * rs) * g[i] + bn[i];
    }
}

// ---------------- launch ----------------
extern "C" void kernel_launch(void* const* d_in, const int* in_sizes, int n_in,
                              void* d_out, int out_size, void* d_ws, size_t ws_size,
                              hipStream_t stream) {
    const float* x    = (const float*)d_in[0];
    const float* cond = (const float*)d_in[1];
    const float* Wq   = (const float*)d_in[2];
    const float* bq   = (const float*)d_in[3];
    const float* Wv   = (const float*)d_in[4];
    const float* bv   = (const float*)d_in[5];
    const float* Wk   = (const float*)d_in[6];
    const float* bk   = (const float*)d_in[7];
    const float* Wo   = (const float*)d_in[8];
    const float* bo   = (const float*)d_in[9];
    const float* g1   = (const float*)d_in[10];
    const float* bn1  = (const float*)d_in[11];
    const float* g2   = (const float*)d_in[12];
    const float* bn2  = (const float*)d_in[13];
    const float* Wf1  = (const float*)d_in[14];
    const float* bf1  = (const float*)d_in[15];
    const float* Wf2  = (const float*)d_in[16];
    const float* bf2  = (const float*)d_in[17];
    float* out = (float*)d_out;

    char* ws = (char*)d_ws;
    // weights (bf16)
    bf16* Wq_b  = (bf16*)(ws + 0);           // 2,163,200
    bf16* Wv_b  = (bf16*)(ws + 2163200);
    bf16* Wk_b  = (bf16*)(ws + 4326400);     // 17,305,600
    bf16* Wo_b  = (bf16*)(ws + 21632000);    // 2,163,200
    bf16* Wf1_b = (bf16*)(ws + 23795200);    // 8,388,608
    bf16* Wf2_b = (bf16*)(ws + 32183808);    // 8,388,608 -> 40,572,416
    bf16*  xc  = (bf16*)(ws + 40572416);     // 17,039,360 -> 57,611,776
    bf16*  ob  = (bf16*)(ws + 57611776);     // 17,039,360 -> 74,651,136
    bf16*  vb  = (bf16*)(ws + 74651136);     // 17,039,360 slot (vb pre-attn, hb post-attn)
    bf16*  hb  = (bf16*)(ws + 74651136);     //            -> 91,690,496
    bf16*  qp  = (bf16*)(ws + 91690496);     // 25,165,824 -> 116,856,320
    bf16*  kp  = (bf16*)(ws + 116856320);    // 25,165,824 -> 142,022,144
    bf16*  vtb = (bf16*)(ws + 142022144);    // 20,971,520 -> 162,993,664
    bf16*  ff1 = (bf16*)(ws + 91690496);     // alias over qp/kp/vt (67,108,864)
    float* zb  = (float*)(ws + 40572416);    // alias over xc+ob (33,554,432)

    // weight conversions
    k_cvt<<<(1081600 / 4 + 255) / 256, 256, 0, stream>>>(Wq, Wq_b, 1081600);
    k_cvt<<<(1081600 / 4 + 255) / 256, 256, 0, stream>>>(Wv, Wv_b, 1081600);
    k_cvt<<<(8652800 / 4 + 255) / 256, 256, 0, stream>>>(Wk, Wk_b, 8652800);
    k_cvt<<<(1081600 / 4 + 255) / 256, 256, 0, stream>>>(Wo, Wo_b, 1081600);
    k_cvt<<<(4194304 / 4 + 255) / 256, 256, 0, stream>>>(Wf1, Wf1_b, 4194304);
    k_cvt<<<(4194304 / 4 + 255) / 256, 256, 0, stream>>>(Wf2, Wf2_b, 4194304);

    k_ln_concat<<<M_, 256, 0, stream>>>(x, cond, g1, bn1, xc);

    // zero qp/kp/vt span (contiguous 71,303,168 B)
    k_zero<<<(4456448 + 255) / 256, 256, 0, stream>>>((uint4*)(ws + 91690496), 4456448);

    dim3 g_qkv((D_ + 127) / 128, M_ / 128);
    k_gemm<EP_Q><<<g_qkv, 256, 0, stream>>>(xc, Wq_b, bq, M_, D_, D_, D_, D_,
                                            qp, nullptr, 0, nullptr, 0, nullptr, nullptr);
    k_gemm<EP_V><<<g_qkv, 256, 0, stream>>>(xc, Wv_b, bv, M_, D_, D_, D_, D_,
                                            vb, nullptr, D_, nullptr, 0, nullptr, nullptr);
    k_gemm<EP_K><<<g_qkv, 256, 0, stream>>>(xc, Wk_b, nullptr, M_, D_, D_, D_, D_,
                                            kp, nullptr, 0, nullptr, 0, cond, bk);

    k_transpose_v<<<dim3(S_ / 64, 64), 256, 0, stream>>>(vb, vtb);

    k_attn<<<dim3(S_ / 64, 64), 256, 0, stream>>>(qp, kp, vtb, ob);

    dim3 g_o(E_ / 128, M_ / 128);
    k_gemm<EP_O><<<g_o, 256, 0, stream>>>(ob, Wo_b, bo, M_, E_, D_, D_, D_,
                                          hb, nullptr, E_, xc, D_, nullptr, nullptr);

    dim3 g_f1(DFF_ / 128, M_ / 128);
    k_gemm<EP_FF1><<<g_f1, 256, 0, stream>>>(hb, Wf1_b, bf1, M_, DFF_, E_, E_, E_,
                                             ff1, nullptr, DFF_, nullptr, 0, nullptr, nullptr);

    dim3 g_f2(E_ / 128, M_ / 128);
    k_gemm<EP_FF2><<<g_f2, 256, 0, stream>>>(ff1, Wf2_b, bf2, M_, E_, DFF_, DFF_, DFF_,
                                             nullptr, zb, E_, hb, E_, nullptr, nullptr);

    k_ln_out<<<M_, 256, 0, stream>>>(zb, g2, bn2, out);
}

// Round 3
// 1181.339 us; speedup vs baseline: 1.3720x; 1.3720x over previous
//
#include <hip/hip_runtime.h>
#include <hip/hip_bf16.h>
#include <math.h>

typedef __bf16 bf16;
typedef __bf16 v8bf __attribute__((ext_vector_type(8)));
typedef float v4f __attribute__((ext_vector_type(4)));

#define B_   4
#define S_   2048
#define E_   1024
#define CS_  16
#define NC_  8
#define H_   16
#define D_   1040
#define DH_  65
#define DFF_ 4096
#define M_   8192

__device__ __forceinline__ v4f mfma16(v8bf a, v8bf b, v4f c) {
    return __builtin_amdgcn_mfma_f32_16x16x32_bf16(a, b, c, 0, 0, 0);
}

// async global->LDS, 16B per lane. LDS side must be wave-uniform base + lane*16.
__device__ __forceinline__ void async16(const bf16* g, bf16* l) {
    __builtin_amdgcn_global_load_lds(
        (const __attribute__((address_space(1))) unsigned int*)g,
        (__attribute__((address_space(3))) unsigned int*)l, 16, 0, 0);
}

// ---------------- f32 -> bf16 weight conversion ----------------
__global__ __launch_bounds__(256) void k_cvt(const float* __restrict__ src,
                                             bf16* __restrict__ dst, int n) {
    int i = (blockIdx.x * 256 + threadIdx.x) * 4;
    if (i + 4 <= n) {
        float4 v = *(const float4*)(src + i);
        bf16 o[4] = {(bf16)v.x, (bf16)v.y, (bf16)v.z, (bf16)v.w};
        *(ushort4*)(dst + i) = *(const ushort4*)o;
    }
}

// ---------------- zero fill ----------------
__global__ __launch_bounds__(256) void k_zero(uint4* __restrict__ p, int n4) {
    int i = blockIdx.x * 256 + threadIdx.x;
    uint4 z = {0u, 0u, 0u, 0u};
    if (i < n4) p[i] = z;
}

// ---------------- LayerNorm(x f32) + concat cond -> xc (M x D) bf16 ----------------
__global__ __launch_bounds__(256) void k_ln_concat(
    const float* __restrict__ x, const float* __restrict__ cond,
    const float* __restrict__ g, const float* __restrict__ bn,
    bf16* __restrict__ xc)
{
    int row = blockIdx.x;
    int t = threadIdx.x;
    const float* xr = x + (size_t)row * E_;
    float4 v = *(const float4*)(xr + t * 4);
    float s = v.x + v.y + v.z + v.w;
    float ss = v.x * v.x + v.y * v.y + v.z * v.z + v.w * v.w;
#pragma unroll
    for (int off = 32; off; off >>= 1) {
        s  += __shfl_down(s, off);
        ss += __shfl_down(ss, off);
    }
    __shared__ float red[8];
    int wid = t >> 6;
    if ((t & 63) == 0) { red[wid] = s; red[4 + wid] = ss; }
    __syncthreads();
    float stot  = red[0] + red[1] + red[2] + red[3];
    float sstot = red[4] + red[5] + red[6] + red[7];
    float mean = stot * (1.0f / E_);
    float var  = sstot * (1.0f / E_) - mean * mean;
    float rs = rsqrtf(var + 1e-5f);
    bf16* xcr = xc + (size_t)row * D_;
    float vv[4] = {v.x, v.y, v.z, v.w};
#pragma unroll
    for (int j = 0; j < 4; ++j) {
        int i = t * 4 + j;
        xcr[i] = (bf16)(((vv[j] - mean) * rs) * g[i] + bn[i]);
    }
    if (t < CS_) xcr[E_ + t] = (bf16)cond[(size_t)row * CS_ + t];
}

// ---------------- GEMM: C[m,n] = sum_k A[m,k]*B[n,k] + epilogue ----------------
#define EP_QV  0
#define EP_K   1
#define EP_O   2
#define EP_FF1 3
#define EP_FF2 4

template<int EP>
__global__ __launch_bounds__(256) void k_gemm(
    const bf16* __restrict__ A, const bf16* __restrict__ Bm,
    const float* __restrict__ bias, const float* __restrict__ bias2,
    int M, int N, int K, int lda, int ldb, int nbn,
    bf16* __restrict__ Cb, float* __restrict__ Cf, int ldc,
    const bf16* __restrict__ res, int ldres,
    const float* __restrict__ condw, const float* __restrict__ bkp)
{
    __shared__ bf16 As[128][32];
    __shared__ bf16 Bs[128][32];
    int t = threadIdx.x;

    // L2 swizzle: groups of GM=8 m-blocks spanning all n-blocks (nbm=M/128 always %8==0)
    int pid = blockIdx.x;
    int nig = 8 * nbn;
    int gid = pid / nig;
    int rem = pid - gid * nig;
    int mi = gid * 8 + (rem & 7);
    int ni = rem >> 3;
    int m0 = mi << 7, n0 = ni << 7;

    int lane = t & 63, w = t >> 6;
    int wm = (w >> 1) * 64, wn = (w & 1) * 64;
    int lr = lane & 15, lq = lane >> 4;

    // staging indices (idx = t + i*256): row = idx>>2, seg = idx&3
    int row_i[2], seg_i[2];
#pragma unroll
    for (int i = 0; i < 2; ++i) { row_i[i] = (t + i * 256) >> 2; seg_i[i] = (t + i * 256) & 3; }

    v4f acc[4][4];
    v4f vzero = {0.f, 0.f, 0.f, 0.f};
#pragma unroll
    for (int mt = 0; mt < 4; ++mt)
#pragma unroll
        for (int nt = 0; nt < 4; ++nt) acc[mt][nt] = vzero;

    const int KF = K >> 5;
    const bool KR = (K & 31) != 0;
    const int CLOOP = (EP == EP_K) ? NC_ : 1;

    for (int c = 0; c < CLOOP; ++c) {
        const bf16* Bc = (EP == EP_K) ? (Bm + (size_t)c * D_ * D_) : Bm;
        float wsc[2];
        if constexpr (EP == EP_K) {
#pragma unroll
            for (int i = 0; i < 2; ++i) wsc[i] = condw[(size_t)(m0 + row_i[i]) * CS_ + c];
        }
        for (int kb = 0; kb < KF; ++kb) {
            int k0 = kb << 5;
            if constexpr (EP == EP_K) {
#pragma unroll
                for (int i = 0; i < 2; ++i) {
                    uint4 val = *(const uint4*)(A + (size_t)(m0 + row_i[i]) * lda + k0 + seg_i[i] * 8);
                    union { uint4 u; bf16 h[8]; } u8;
                    u8.u = val;
#pragma unroll
                    for (int j = 0; j < 8; ++j) u8.h[j] = (bf16)((float)u8.h[j] * wsc[i]);
                    *(uint4*)(&As[row_i[i]][seg_i[i] * 8]) = u8.u;
                }
            } else {
#pragma unroll
                for (int i = 0; i < 2; ++i)
                    async16(A + (size_t)(m0 + row_i[i]) * lda + k0 + seg_i[i] * 8,
                            &As[0][0] + (t + i * 256) * 8);
            }
#pragma unroll
            for (int i = 0; i < 2; ++i)
                async16(Bc + (size_t)(n0 + row_i[i]) * ldb + k0 + seg_i[i] * 8,
                        &Bs[0][0] + (t + i * 256) * 8);
            __syncthreads();
            v8bf af[4], bfr[4];
#pragma unroll
            for (int mt = 0; mt < 4; ++mt) af[mt]  = *(const v8bf*)(&As[wm + mt * 16 + lr][lq * 8]);
#pragma unroll
            for (int nt = 0; nt < 4; ++nt) bfr[nt] = *(const v8bf*)(&Bs[wn + nt * 16 + lr][lq * 8]);
#pragma unroll
            for (int mt = 0; mt < 4; ++mt)
#pragma unroll
                for (int nt = 0; nt < 4; ++nt)
                    acc[mt][nt] = mfma16(af[mt], bfr[nt], acc[mt][nt]);
            __syncthreads();
        }
        if (KR) { // remainder K-tile: predicated VGPR path with zero fill
            int k0 = KF << 5;
#pragma unroll
            for (int i = 0; i < 2; ++i) {
                int gk = k0 + seg_i[i] * 8;
                uint4 val = {0u, 0u, 0u, 0u};
                if (gk + 8 <= K) val = *(const uint4*)(A + (size_t)(m0 + row_i[i]) * lda + gk);
                if constexpr (EP == EP_K) {
                    union { uint4 u; bf16 h[8]; } u8;
                    u8.u = val;
#pragma unroll
                    for (int j = 0; j < 8; ++j) u8.h[j] = (bf16)((float)u8.h[j] * wsc[i]);
                    val = u8.u;
                }
                *(uint4*)(&As[row_i[i]][seg_i[i] * 8]) = val;
                uint4 bv = {0u, 0u, 0u, 0u};
                int gn = n0 + row_i[i];
                if (gn < N && gk + 8 <= K) bv = *(const uint4*)(Bc + (size_t)gn * ldb + gk);
                *(uint4*)(&Bs[row_i[i]][seg_i[i] * 8]) = bv;
            }
            __syncthreads();
            v8bf af[4], bfr[4];
#pragma unroll
            for (int mt = 0; mt < 4; ++mt) af[mt]  = *(const v8bf*)(&As[wm + mt * 16 + lr][lq * 8]);
#pragma unroll
            for (int nt = 0; nt < 4; ++nt) bfr[nt] = *(const v8bf*)(&Bs[wn + nt * 16 + lr][lq * 8]);
#pragma unroll
            for (int mt = 0; mt < 4; ++mt)
#pragma unroll
                for (int nt = 0; nt < 4; ++nt)
                    acc[mt][nt] = mfma16(af[mt], bfr[nt], acc[mt][nt]);
            __syncthreads();
        }
    }

    // epilogue: row = m0+wm+mt*16+lq*4+reg, col = n0+wn+nt*16+lr
#pragma unroll
    for (int mt = 0; mt < 4; ++mt) {
#pragma unroll
        for (int reg = 0; reg < 4; ++reg) {
            int grow = m0 + wm + mt * 16 + lq * 4 + reg;
#pragma unroll
            for (int nt = 0; nt < 4; ++nt) {
                int gcol = n0 + wn + nt * 16 + lr;
                float vacc = acc[mt][nt][reg];
                if constexpr (EP == EP_QV) {
                    if (gcol < D_) { // Q -> qp padded layout, pre-scaled
                        float o = (vacc + bias[gcol]) * 0.1240347346f; // 1/sqrt(65)
                        int h = gcol / 65, d = gcol - h * 65;
                        int b = grow >> 11, s = grow & 2047;
                        Cb[(((size_t)(b * 16 + h)) * S_ + s) * 96 + d] = (bf16)o;
                    } else if (gcol < 2 * D_) { // V -> vb row-major
                        int col = gcol - D_;
                        Cf[(size_t)0] = Cf[(size_t)0]; // no-op keep type
                        ((bf16*)res)[(size_t)grow * D_ + col] = (bf16)(vacc + bias2[col]);
                    }
                } else if constexpr (EP == EP_K) {
                    if (gcol < D_) {
                        float bb = 0.f;
#pragma unroll
                        for (int cc = 0; cc < NC_; ++cc)
                            bb += condw[(size_t)grow * CS_ + cc] * bkp[(size_t)cc * D_ + gcol];
                        float o = vacc + bb;
                        int h = gcol / 65, d = gcol - h * 65;
                        int b = grow >> 11, s = grow & 2047;
                        Cb[(((size_t)(b * 16 + h)) * S_ + s) * 96 + d] = (bf16)o;
                    }
                } else if constexpr (EP == EP_O) {
                    float o = vacc + bias[gcol] + (float)res[(size_t)grow * ldres + gcol];
                    Cb[(size_t)grow * ldc + gcol] = (bf16)o;
                } else if constexpr (EP == EP_FF1) {
                    float o = vacc + bias[gcol];
                    Cb[(size_t)grow * ldc + gcol] = (bf16)fmaxf(o, 0.f);
                } else { // EP_FF2
                    Cf[(size_t)grow * ldc + gcol] =
                        vacc + bias[gcol] + (float)res[(size_t)grow * ldres + gcol];
                }
            }
        }
    }
}

// ---------------- transpose v (M x D bf16) into vt [bh][d(80)][s] ----------------
__global__ __launch_bounds__(256) void k_transpose_v(
    const bf16* __restrict__ v, bf16* __restrict__ vt)
{
    int bh = blockIdx.y, s0 = blockIdx.x * 64;
    int b = bh >> 4, h = bh & 15;
    __shared__ bf16 tile[80][65];
#pragma unroll
    for (int i = 0; i < 20; ++i) {
        int idx = threadIdx.x + i * 256;
        int d = idx % 80, sl = idx / 80;
        bf16 val = (bf16)0.f;
        if (d < DH_) val = v[((size_t)b * S_ + s0 + sl) * D_ + h * DH_ + d];
        tile[d][sl] = val;
    }
    __syncthreads();
#pragma unroll
    for (int i = 0; i < 20; ++i) {
        int idx = threadIdx.x + i * 256;
        int sl = idx % 64, d = idx / 64;
        vt[((size_t)bh * 80 + d) * S_ + s0 + sl] = tile[d][sl];
    }
}

// ---------------- flash attention ----------------
__global__ __launch_bounds__(256) void k_attn(
    const bf16* __restrict__ qp, const bf16* __restrict__ kp,
    const bf16* __restrict__ vt, bf16* __restrict__ o)
{
    int bh = blockIdx.y;
    int s0 = blockIdx.x * 64;
    int b = bh >> 4, h = bh & 15;
    int t = threadIdx.x, lane = t & 63, w = t >> 6;
    int lr = lane & 15, lq = lane >> 4;

    __shared__ bf16 Qs[64][96];
    __shared__ bf16 Ks[64][96];
    __shared__ bf16 Vs[80][64];
    __shared__ bf16 Ps[4][16][64];

    const bf16* qbase = qp + ((size_t)bh * S_ + s0) * 96;
#pragma unroll
    for (int i = 0; i < 3; ++i) {
        int idx = t + i * 256;
        int row = idx / 12, seg = idx % 12;
        *(uint4*)(&Qs[row][seg * 8]) = *(const uint4*)(qbase + (size_t)row * 96 + seg * 8);
    }

    float m_r[4], l_r[4];
    v4f o_acc[5];
    v4f vzero = {0.f, 0.f, 0.f, 0.f};
#pragma unroll
    for (int r = 0; r < 4; ++r) { m_r[r] = -1e30f; l_r[r] = 0.f; }
#pragma unroll
    for (int nt = 0; nt < 5; ++nt) o_acc[nt] = vzero;

    for (int kb = 0; kb < S_ / 64; ++kb) {
        const bf16* kbase = kp + ((size_t)bh * S_ + kb * 64) * 96;
#pragma unroll
        for (int i = 0; i < 3; ++i) {
            int idx = t + i * 256;
            int row = idx / 12, seg = idx % 12;
            *(uint4*)(&Ks[row][seg * 8]) = *(const uint4*)(kbase + (size_t)row * 96 + seg * 8);
        }
#pragma unroll
        for (int i = 0; i < 3; ++i) {
            int idx = t + i * 256;
            if (idx < 640) {
                int d = idx >> 3, seg = idx & 7;
                *(uint4*)(&Vs[d][seg * 8]) =
                    *(const uint4*)(vt + ((size_t)bh * 80 + d) * S_ + kb * 64 + seg * 8);
            }
        }
        __syncthreads();

        v4f sacc[4];
#pragma unroll
        for (int nt = 0; nt < 4; ++nt) sacc[nt] = vzero;
#pragma unroll
        for (int ks = 0; ks < 3; ++ks) {
            v8bf aq = *(const v8bf*)(&Qs[w * 16 + lr][ks * 32 + lq * 8]);
#pragma unroll
            for (int nt = 0; nt < 4; ++nt) {
                v8bf bk2 = *(const v8bf*)(&Ks[nt * 16 + lr][ks * 32 + lq * 8]);
                sacc[nt] = mfma16(aq, bk2, sacc[nt]);
            }
        }

        float alpha[4];
#pragma unroll
        for (int r = 0; r < 4; ++r) {
            float mx = fmaxf(fmaxf(sacc[0][r], sacc[1][r]), fmaxf(sacc[2][r], sacc[3][r]));
#pragma unroll
            for (int off = 1; off < 16; off <<= 1) mx = fmaxf(mx, __shfl_xor(mx, off));
            float mnew = fmaxf(m_r[r], mx);
            alpha[r] = __expf(m_r[r] - mnew);
            float ps = 0.f;
#pragma unroll
            for (int nt = 0; nt < 4; ++nt) {
                float p = __expf(sacc[nt][r] - mnew);
                sacc[nt][r] = p;
                ps += p;
            }
#pragma unroll
            for (int off = 1; off < 16; off <<= 1) ps += __shfl_xor(ps, off);
            l_r[r] = l_r[r] * alpha[r] + ps;
            m_r[r] = mnew;
        }

#pragma unroll
        for (int nt = 0; nt < 4; ++nt)
#pragma unroll
            for (int r = 0; r < 4; ++r)
                Ps[w][lq * 4 + r][nt * 16 + lr] = (bf16)sacc[nt][r];
        asm volatile("s_waitcnt lgkmcnt(0)" ::: "memory");

#pragma unroll
        for (int nt = 0; nt < 5; ++nt)
#pragma unroll
            for (int r = 0; r < 4; ++r) o_acc[nt][r] *= alpha[r];

#pragma unroll
        for (int kt = 0; kt < 2; ++kt) {
            v8bf ap = *(const v8bf*)(&Ps[w][lr][kt * 32 + lq * 8]);
#pragma unroll
            for (int nt = 0; nt < 5; ++nt) {
                v8bf bv2 = *(const v8bf*)(&Vs[nt * 16 + lr][kt * 32 + lq * 8]);
                o_acc[nt] = mfma16(ap, bv2, o_acc[nt]);
            }
        }
        __syncthreads();
    }

    int token = b * S_ + s0 + w * 16 + lq * 4;
#pragma unroll
    for (int nt = 0; nt < 5; ++nt) {
        int d = nt * 16 + lr;
        if (d < DH_) {
#pragma unroll
            for (int r = 0; r < 4; ++r)
                o[(size_t)(token + r) * D_ + h * DH_ + d] = (bf16)(o_acc[nt][r] / l_r[r]);
        }
    }
}

// ---------------- final LayerNorm on z (f32) -> out f32 ----------------
__global__ __launch_bounds__(256) void k_ln_out(
    const float* __restrict__ z, const float* __restrict__ g,
    const float* __restrict__ bn, float* __restrict__ out)
{
    int row = blockIdx.x;
    int t = threadIdx.x;
    const float* zr = z + (size_t)row * E_;
    float4 v = *(const float4*)(zr + t * 4);
    float s = v.x + v.y + v.z + v.w;
    float ss = v.x * v.x + v.y * v.y + v.z * v.z + v.w * v.w;
#pragma unroll
    for (int off = 32; off; off >>= 1) {
        s  += __shfl_down(s, off);
        ss += __shfl_down(ss, off);
    }
    __shared__ float red[8];
    int wid = t >> 6;
    if ((t & 63) == 0) { red[wid] = s; red[4 + wid] = ss; }
    __syncthreads();
    float stot  = red[0] + red[1] + red[2] + red[3];
    float sstot = red[4] + red[5] + red[6] + red[7];
    float mean = stot * (1.0f / E_);
    float var  = sstot * (1.0f / E_) - mean * mean;
    float rs = rsqrtf(var + 1e-5f);
    float* outr = out + (size_t)row * E_;
    float vv[4] = {v.x, v.y, v.z, v.w};
#pragma unroll
    for (int j = 0; j < 4; ++j) {
        int i = t * 4 + j;
        outr[i] = ((vv[j] - mean) * rs) * g[i] + bn[i];
    }
}

// ---------------- launch ----------------
extern "C" void kernel_launch(void* const* d_in, const int* in_sizes, int n_in,
                              void* d_out, int out_size, void* d_ws, size_t ws_size,
                              hipStream_t stream) {
    const float* x    = (const float*)d_in[0];
    const float* cond = (const float*)d_in[1];
    const float* Wq   = (const float*)d_in[2];
    const float* bq   = (const float*)d_in[3];
    const float* Wv   = (const float*)d_in[4];
    const float* bv   = (const float*)d_in[5];
    const float* Wk   = (const float*)d_in[6];
    const float* bk   = (const float*)d_in[7];
    const float* Wo   = (const float*)d_in[8];
    const float* bo   = (const float*)d_in[9];
    const float* g1   = (const float*)d_in[10];
    const float* bn1  = (const float*)d_in[11];
    const float* g2   = (const float*)d_in[12];
    const float* bn2  = (const float*)d_in[13];
    const float* Wf1  = (const float*)d_in[14];
    const float* bf1  = (const float*)d_in[15];
    const float* Wf2  = (const float*)d_in[16];
    const float* bf2  = (const float*)d_in[17];
    float* out = (float*)d_out;

    char* ws = (char*)d_ws;
    bf16* Wqv_b = (bf16*)(ws + 0);           // 2176x1040x2 = 4,526,080
    bf16* Wk_b  = (bf16*)(ws + 4526080);     // 17,305,600 -> 21,831,680
    bf16* Wo_b  = (bf16*)(ws + 21831680);    //  2,163,200 -> 23,994,880
    bf16* Wf1_b = (bf16*)(ws + 23994880);    //  8,388,608 -> 32,383,488
    bf16* Wf2_b = (bf16*)(ws + 32383488);    //  8,388,608 -> 40,772,096
    bf16*  xc  = (bf16*)(ws + 40772096);     // 17,039,360 -> 57,811,456
    bf16*  ob  = (bf16*)(ws + 57811456);     // 17,039,360 -> 74,850,816
    bf16*  vb  = (bf16*)(ws + 74850816);     // vb pre-attn / hb post-attn
    bf16*  hb  = (bf16*)(ws + 74850816);     // 17,039,360 -> 91,890,176
    bf16*  qp  = (bf16*)(ws + 91890176);     // 25,165,824 -> 117,056,000
    bf16*  kp  = (bf16*)(ws + 117056000);    // 25,165,824 -> 142,221,824
    bf16*  vtb = (bf16*)(ws + 142221824);    // 20,971,520 -> 163,193,344
    bf16*  ff1 = (bf16*)(ws + 91890176);     // alias over qp/kp/vt
    float* zb  = (float*)(ws + 40772096);    // alias over xc+ob

    k_cvt<<<(1081600 / 4 + 255) / 256, 256, 0, stream>>>(Wq, Wqv_b, 1081600);
    k_cvt<<<(1081600 / 4 + 255) / 256, 256, 0, stream>>>(Wv, Wqv_b + 1081600, 1081600);
    k_cvt<<<(8652800 / 4 + 255) / 256, 256, 0, stream>>>(Wk, Wk_b, 8652800);
    k_cvt<<<(1081600 / 4 + 255) / 256, 256, 0, stream>>>(Wo, Wo_b, 1081600);
    k_cvt<<<(4194304 / 4 + 255) / 256, 256, 0, stream>>>(Wf1, Wf1_b, 4194304);
    k_cvt<<<(4194304 / 4 + 255) / 256, 256, 0, stream>>>(Wf2, Wf2_b, 4194304);

    k_ln_concat<<<M_, 256, 0, stream>>>(x, cond, g1, bn1, xc);

    // zero qp/kp/vt span (pads must be 0)
    k_zero<<<(4456448 + 255) / 256, 256, 0, stream>>>((uint4*)(ws + 91890176), 4456448);

    // fused Q+V: N=2080 logical (B rows 2176 allocated), writes qp + vb
    k_gemm<EP_QV><<<64 * 17, 256, 0, stream>>>(xc, Wqv_b, bq, bv, M_, 2 * D_, D_, D_, D_, 17,
                                               qp, (float*)vb, 0, (const bf16*)vb, 0, nullptr, nullptr);
    k_gemm<EP_K><<<64 * 9, 256, 0, stream>>>(xc, Wk_b, nullptr, nullptr, M_, D_, D_, D_, D_, 9,
                                             kp, nullptr, 0, nullptr, 0, cond, bk);

    k_transpose_v<<<dim3(S_ / 64, 64), 256, 0, stream>>>(vb, vtb);
    k_attn<<<dim3(S_ / 64, 64), 256, 0, stream>>>(qp, kp, vtb, ob);

    k_gemm<EP_O><<<64 * 8, 256, 0, stream>>>(ob, Wo_b, bo, nullptr, M_, E_, D_, D_, D_, 8,
                                             hb, nullptr, E_, xc, D_, nullptr, nullptr);
    k_gemm<EP_FF1><<<64 * 32, 256, 0, stream>>>(hb, Wf1_b, bf1, nullptr, M_, DFF_, E_, E_, E_, 32,
                                                ff1, nullptr, DFF_, nullptr, 0, nullptr, nullptr);
    k_gemm<EP_FF2><<<64 * 8, 256, 0, stream>>>(ff1, Wf2_b, bf2, nullptr, M_, E_, DFF_, DFF_, DFF_, 8,
                                               nullptr, zb, E_, hb, E_, nullptr, nullptr);

    k_ln_out<<<M_, 256, 0, stream>>>(zb, g2, bn2, out);
}

// Round 4
// 1094.998 us; speedup vs baseline: 1.4802x; 1.0789x over previous
//
#include <hip/hip_runtime.h>
#include <hip/hip_bf16.h>
#include <math.h>

typedef __bf16 bf16;
typedef __bf16 v8bf __attribute__((ext_vector_type(8)));
typedef float v4f __attribute__((ext_vector_type(4)));

#define B_   4
#define S_   2048
#define E_   1024
#define CS_  16
#define NC_  8
#define H_   16
#define D_   1040
#define DH_  65
#define DFF_ 4096
#define M_   8192

__device__ __forceinline__ v4f mfma16(v8bf a, v8bf b, v4f c) {
    return __builtin_amdgcn_mfma_f32_16x16x32_bf16(a, b, c, 0, 0, 0);
}

// async global->LDS, 16B per lane. LDS side must be wave-uniform base + lane*16.
__device__ __forceinline__ void async16(const bf16* g, bf16* l) {
    __builtin_amdgcn_global_load_lds(
        (const __attribute__((address_space(1))) unsigned int*)g,
        (__attribute__((address_space(3))) unsigned int*)l, 16, 0, 0);
}

// ---------------- f32 -> bf16 weight conversion ----------------
__global__ __launch_bounds__(256) void k_cvt(const float* __restrict__ src,
                                             bf16* __restrict__ dst, int n) {
    int i = (blockIdx.x * 256 + threadIdx.x) * 4;
    if (i + 4 <= n) {
        float4 v = *(const float4*)(src + i);
        bf16 o[4] = {(bf16)v.x, (bf16)v.y, (bf16)v.z, (bf16)v.w};
        *(ushort4*)(dst + i) = *(const ushort4*)o;
    }
}

// ---------------- zero fill ----------------
__global__ __launch_bounds__(256) void k_zero(uint4* __restrict__ p, int n4) {
    int i = blockIdx.x * 256 + threadIdx.x;
    uint4 z = {0u, 0u, 0u, 0u};
    if (i < n4) p[i] = z;
}

// ---------------- LayerNorm(x f32) + concat cond -> xc (M x D) bf16 ----------------
__global__ __launch_bounds__(256) void k_ln_concat(
    const float* __restrict__ x, const float* __restrict__ cond,
    const float* __restrict__ g, const float* __restrict__ bn,
    bf16* __restrict__ xc)
{
    int row = blockIdx.x;
    int t = threadIdx.x;
    const float* xr = x + (size_t)row * E_;
    float4 v = *(const float4*)(xr + t * 4);
    float s = v.x + v.y + v.z + v.w;
    float ss = v.x * v.x + v.y * v.y + v.z * v.z + v.w * v.w;
#pragma unroll
    for (int off = 32; off; off >>= 1) {
        s  += __shfl_down(s, off);
        ss += __shfl_down(ss, off);
    }
    __shared__ float red[8];
    int wid = t >> 6;
    if ((t & 63) == 0) { red[wid] = s; red[4 + wid] = ss; }
    __syncthreads();
    float stot  = red[0] + red[1] + red[2] + red[3];
    float sstot = red[4] + red[5] + red[6] + red[7];
    float mean = stot * (1.0f / E_);
    float var  = sstot * (1.0f / E_) - mean * mean;
    float rs = rsqrtf(var + 1e-5f);
    bf16* xcr = xc + (size_t)row * D_;
    float vv[4] = {v.x, v.y, v.z, v.w};
#pragma unroll
    for (int j = 0; j < 4; ++j) {
        int i = t * 4 + j;
        xcr[i] = (bf16)(((vv[j] - mean) * rs) * g[i] + bn[i]);
    }
    if (t < CS_) xcr[E_ + t] = (bf16)cond[(size_t)row * CS_ + t];
}

// ---------------- GEMM: C[m,n] = sum_k A[m,k]*B[n,k] + epilogue ----------------
#define EP_QV  0
#define EP_K   1
#define EP_O   2
#define EP_FF1 3
#define EP_FF2 4

template<int EP>
__global__ __launch_bounds__(256) void k_gemm(
    const bf16* __restrict__ A, const bf16* __restrict__ Bm,
    const float* __restrict__ bias, const float* __restrict__ bias2,
    int M, int N, int K, int lda, int ldb, int nbn,
    bf16* __restrict__ Cb, float* __restrict__ Cf, int ldc,
    const bf16* __restrict__ res, int ldres,
    const float* __restrict__ condw, const float* __restrict__ bkp)
{
    __shared__ bf16 As[128][32];
    __shared__ bf16 Bs[128][32];
    int t = threadIdx.x;

    // L2 swizzle: groups of GM=8 m-blocks spanning all n-blocks
    int pid = blockIdx.x;
    int nig = 8 * nbn;
    int gid = pid / nig;
    int rem = pid - gid * nig;
    int mi = gid * 8 + (rem & 7);
    int ni = rem >> 3;
    int m0 = mi << 7, n0 = ni << 7;

    int lane = t & 63, w = t >> 6;
    int wm = (w >> 1) * 64, wn = (w & 1) * 64;
    int lr = lane & 15, lq = lane >> 4;

    int row_i[2], seg_i[2];
#pragma unroll
    for (int i = 0; i < 2; ++i) { row_i[i] = (t + i * 256) >> 2; seg_i[i] = (t + i * 256) & 3; }

    v4f acc[4][4];
    v4f vzero = {0.f, 0.f, 0.f, 0.f};
#pragma unroll
    for (int mt = 0; mt < 4; ++mt)
#pragma unroll
        for (int nt = 0; nt < 4; ++nt) acc[mt][nt] = vzero;

    const int KF = K >> 5;
    const bool KR = (K & 31) != 0;
    const int CLOOP = (EP == EP_K) ? NC_ : 1;

    for (int c = 0; c < CLOOP; ++c) {
        const bf16* Bc = (EP == EP_K) ? (Bm + (size_t)c * D_ * D_) : Bm;
        float wsc[2];
        if constexpr (EP == EP_K) {
#pragma unroll
            for (int i = 0; i < 2; ++i) wsc[i] = condw[(size_t)(m0 + row_i[i]) * CS_ + c];
        }
        for (int kb = 0; kb < KF; ++kb) {
            int k0 = kb << 5;
            if constexpr (EP == EP_K) {
#pragma unroll
                for (int i = 0; i < 2; ++i) {
                    uint4 val = *(const uint4*)(A + (size_t)(m0 + row_i[i]) * lda + k0 + seg_i[i] * 8);
                    union { uint4 u; bf16 h[8]; } u8;
                    u8.u = val;
#pragma unroll
                    for (int j = 0; j < 8; ++j) u8.h[j] = (bf16)((float)u8.h[j] * wsc[i]);
                    *(uint4*)(&As[row_i[i]][seg_i[i] * 8]) = u8.u;
                }
            } else {
#pragma unroll
                for (int i = 0; i < 2; ++i)
                    async16(A + (size_t)(m0 + row_i[i]) * lda + k0 + seg_i[i] * 8,
                            &As[0][0] + (t + i * 256) * 8);
            }
#pragma unroll
            for (int i = 0; i < 2; ++i)
                async16(Bc + (size_t)(n0 + row_i[i]) * ldb + k0 + seg_i[i] * 8,
                        &Bs[0][0] + (t + i * 256) * 8);
            __syncthreads();
            v8bf af[4], bfr[4];
#pragma unroll
            for (int mt = 0; mt < 4; ++mt) af[mt]  = *(const v8bf*)(&As[wm + mt * 16 + lr][lq * 8]);
#pragma unroll
            for (int nt = 0; nt < 4; ++nt) bfr[nt] = *(const v8bf*)(&Bs[wn + nt * 16 + lr][lq * 8]);
#pragma unroll
            for (int mt = 0; mt < 4; ++mt)
#pragma unroll
                for (int nt = 0; nt < 4; ++nt)
                    acc[mt][nt] = mfma16(af[mt], bfr[nt], acc[mt][nt]);
            __syncthreads();
        }
        if (KR) {
            int k0 = KF << 5;
#pragma unroll
            for (int i = 0; i < 2; ++i) {
                int gk = k0 + seg_i[i] * 8;
                uint4 val = {0u, 0u, 0u, 0u};
                if (gk + 8 <= K) val = *(const uint4*)(A + (size_t)(m0 + row_i[i]) * lda + gk);
                if constexpr (EP == EP_K) {
                    union { uint4 u; bf16 h[8]; } u8;
                    u8.u = val;
#pragma unroll
                    for (int j = 0; j < 8; ++j) u8.h[j] = (bf16)((float)u8.h[j] * wsc[i]);
                    val = u8.u;
                }
                *(uint4*)(&As[row_i[i]][seg_i[i] * 8]) = val;
                uint4 bv = {0u, 0u, 0u, 0u};
                int gn = n0 + row_i[i];
                if (gn < N && gk + 8 <= K) bv = *(const uint4*)(Bc + (size_t)gn * ldb + gk);
                *(uint4*)(&Bs[row_i[i]][seg_i[i] * 8]) = bv;
            }
            __syncthreads();
            v8bf af[4], bfr[4];
#pragma unroll
            for (int mt = 0; mt < 4; ++mt) af[mt]  = *(const v8bf*)(&As[wm + mt * 16 + lr][lq * 8]);
#pragma unroll
            for (int nt = 0; nt < 4; ++nt) bfr[nt] = *(const v8bf*)(&Bs[wn + nt * 16 + lr][lq * 8]);
#pragma unroll
            for (int mt = 0; mt < 4; ++mt)
#pragma unroll
                for (int nt = 0; nt < 4; ++nt)
                    acc[mt][nt] = mfma16(af[mt], bfr[nt], acc[mt][nt]);
            __syncthreads();
        }
    }

    // epilogue: row = m0+wm+mt*16+lq*4+reg, col = n0+wn+nt*16+lr
#pragma unroll
    for (int mt = 0; mt < 4; ++mt) {
#pragma unroll
        for (int reg = 0; reg < 4; ++reg) {
            int grow = m0 + wm + mt * 16 + lq * 4 + reg;
#pragma unroll
            for (int nt = 0; nt < 4; ++nt) {
                int gcol = n0 + wn + nt * 16 + lr;
                float vacc = acc[mt][nt][reg];
                if constexpr (EP == EP_QV) {
                    if (gcol < D_) { // Q -> qp padded layout, pre-scaled by log2e/sqrt(65)
                        float o = (vacc + bias[gcol]) * 0.1789442960f;
                        int h = gcol / 65, d = gcol - h * 65;
                        int b = grow >> 11, s = grow & 2047;
                        Cb[(((size_t)(b * 16 + h)) * S_ + s) * 96 + d] = (bf16)o;
                    } else if (gcol < 2 * D_) { // V -> vb row-major
                        int col = gcol - D_;
                        ((bf16*)res)[(size_t)grow * D_ + col] = (bf16)(vacc + bias2[col]);
                    }
                } else if constexpr (EP == EP_K) {
                    if (gcol < D_) {
                        float bb = 0.f;
#pragma unroll
                        for (int cc = 0; cc < NC_; ++cc)
                            bb += condw[(size_t)grow * CS_ + cc] * bkp[(size_t)cc * D_ + gcol];
                        float o = vacc + bb;
                        int h = gcol / 65, d = gcol - h * 65;
                        int b = grow >> 11, s = grow & 2047;
                        Cb[(((size_t)(b * 16 + h)) * S_ + s) * 96 + d] = (bf16)o;
                    }
                } else if constexpr (EP == EP_O) {
                    float o = vacc + bias[gcol] + (float)res[(size_t)grow * ldres + gcol];
                    Cb[(size_t)grow * ldc + gcol] = (bf16)o;
                } else if constexpr (EP == EP_FF1) {
                    float o = vacc + bias[gcol];
                    Cb[(size_t)grow * ldc + gcol] = (bf16)fmaxf(o, 0.f);
                } else { // EP_FF2
                    Cf[(size_t)grow * ldc + gcol] =
                        vacc + bias[gcol] + (float)res[(size_t)grow * ldres + gcol];
                }
            }
        }
    }
}

// ---------------- transpose v (M x D bf16) into vt [bh][d(80)][s] ----------------
__global__ __launch_bounds__(256) void k_transpose_v(
    const bf16* __restrict__ v, bf16* __restrict__ vt)
{
    int bh = blockIdx.y, s0 = blockIdx.x * 64;
    int b = bh >> 4, h = bh & 15;
    __shared__ bf16 tile[80][65];
#pragma unroll
    for (int i = 0; i < 20; ++i) {
        int idx = threadIdx.x + i * 256;
        int d = idx % 80, sl = idx / 80;
        bf16 val = (bf16)0.f;
        if (d < DH_) val = v[((size_t)b * S_ + s0 + sl) * D_ + h * DH_ + d];
        tile[d][sl] = val;
    }
    __syncthreads();
#pragma unroll
    for (int i = 0; i < 20; ++i) {
        int idx = threadIdx.x + i * 256;
        int sl = idx % 64, d = idx / 64;
        vt[((size_t)bh * 80 + d) * S_ + s0 + sl] = tile[d][sl];
    }
}

// ---------------- flash attention (padded LDS, Q in regs, exp2 softmax) ----------------
__global__ __launch_bounds__(256) void k_attn(
    const bf16* __restrict__ qp, const bf16* __restrict__ kp,
    const bf16* __restrict__ vt, bf16* __restrict__ o)
{
    int bh = blockIdx.y;
    int s0 = blockIdx.x * 64;
    int b = bh >> 4, h = bh & 15;
    int t = threadIdx.x, lane = t & 63, w = t >> 6;
    int lr = lane & 15, lq = lane >> 4;

    __shared__ bf16 Ks[64][104];   // stride 208B = 52 banks -> 2-way (free)
    __shared__ bf16 Vs[80][72];    // stride 144B = 36 banks -> 2-way (free)
    __shared__ bf16 QP[64 * 104];  // Q staging, then P tiles [4][16][72]

    // stage Q tile into QP (padded rows of 104), pull per-lane fragments to regs
    const bf16* qbase = qp + ((size_t)bh * S_ + s0) * 96;
#pragma unroll
    for (int i = 0; i < 3; ++i) {
        int idx = t + i * 256;
        int row = idx / 12, seg = idx % 12;
        *(uint4*)(&QP[row * 104 + seg * 8]) = *(const uint4*)(qbase + (size_t)row * 96 + seg * 8);
    }
    __syncthreads();
    v8bf qreg[3];
#pragma unroll
    for (int ks = 0; ks < 3; ++ks)
        qreg[ks] = *(const v8bf*)(&QP[(w * 16 + lr) * 104 + ks * 32 + lq * 8]);
    __syncthreads();  // all Q reads done before QP is reused as P

    bf16* Ps = &QP[w * (16 * 72)];  // per-wave P region, rows of 72

    float m_r[4], l_r[4];
    v4f o_acc[5];
    v4f vzero = {0.f, 0.f, 0.f, 0.f};
#pragma unroll
    for (int r = 0; r < 4; ++r) { m_r[r] = -1e30f; l_r[r] = 0.f; }
#pragma unroll
    for (int nt = 0; nt < 5; ++nt) o_acc[nt] = vzero;

    for (int kb = 0; kb < S_ / 64; ++kb) {
        const bf16* kbase = kp + ((size_t)bh * S_ + kb * 64) * 96;
#pragma unroll
        for (int i = 0; i < 3; ++i) {
            int idx = t + i * 256;
            int row = idx / 12, seg = idx % 12;
            *(uint4*)(&Ks[row][seg * 8]) = *(const uint4*)(kbase + (size_t)row * 96 + seg * 8);
        }
#pragma unroll
        for (int i = 0; i < 3; ++i) {
            int idx = t + i * 256;
            if (idx < 640) {
                int d = idx >> 3, seg = idx & 7;
                *(uint4*)(&Vs[d][seg * 8]) =
                    *(const uint4*)(vt + ((size_t)bh * 80 + d) * S_ + kb * 64 + seg * 8);
            }
        }
        __syncthreads();

        v4f sacc[4];
#pragma unroll
        for (int nt = 0; nt < 4; ++nt) sacc[nt] = vzero;
#pragma unroll
        for (int ks = 0; ks < 3; ++ks) {
#pragma unroll
            for (int nt = 0; nt < 4; ++nt) {
                v8bf bk2 = *(const v8bf*)(&Ks[nt * 16 + lr][ks * 32 + lq * 8]);
                sacc[nt] = mfma16(qreg[ks], bk2, sacc[nt]);
            }
        }

        // online softmax in log2 domain (scores pre-scaled by log2e/sqrt(DH))
        float alpha[4];
#pragma unroll
        for (int r = 0; r < 4; ++r) {
            float mx = fmaxf(fmaxf(sacc[0][r], sacc[1][r]), fmaxf(sacc[2][r], sacc[3][r]));
#pragma unroll
            for (int off = 1; off < 16; off <<= 1) mx = fmaxf(mx, __shfl_xor(mx, off));
            float mnew = fmaxf(m_r[r], mx);
            alpha[r] = __builtin_amdgcn_exp2f(m_r[r] - mnew);
            float ps = 0.f;
#pragma unroll
            for (int nt = 0; nt < 4; ++nt) {
                float p = __builtin_amdgcn_exp2f(sacc[nt][r] - mnew);
                sacc[nt][r] = p;
                ps += p;
            }
#pragma unroll
            for (int off = 1; off < 16; off <<= 1) ps += __shfl_xor(ps, off);
            l_r[r] = l_r[r] * alpha[r] + ps;
            m_r[r] = mnew;
        }

        // P: C-layout -> A-layout via per-wave LDS region (rows padded to 72)
#pragma unroll
        for (int nt = 0; nt < 4; ++nt)
#pragma unroll
            for (int r = 0; r < 4; ++r)
                Ps[(lq * 4 + r) * 72 + nt * 16 + lr] = (bf16)sacc[nt][r];
        asm volatile("s_waitcnt lgkmcnt(0)" ::: "memory");

#pragma unroll
        for (int nt = 0; nt < 5; ++nt)
#pragma unroll
            for (int r = 0; r < 4; ++r) o_acc[nt][r] *= alpha[r];

#pragma unroll
        for (int kt = 0; kt < 2; ++kt) {
            v8bf ap = *(const v8bf*)(&Ps[lr * 72 + kt * 32 + lq * 8]);
#pragma unroll
            for (int nt = 0; nt < 5; ++nt) {
                v8bf bv2 = *(const v8bf*)(&Vs[nt * 16 + lr][kt * 32 + lq * 8]);
                o_acc[nt] = mfma16(ap, bv2, o_acc[nt]);
            }
        }
        __syncthreads();
    }

    float inv[4];
#pragma unroll
    for (int r = 0; r < 4; ++r) inv[r] = 1.0f / l_r[r];
    int token = b * S_ + s0 + w * 16 + lq * 4;
#pragma unroll
    for (int nt = 0; nt < 5; ++nt) {
        int d = nt * 16 + lr;
        if (d < DH_) {
#pragma unroll
            for (int r = 0; r < 4; ++r)
                o[(size_t)(token + r) * D_ + h * DH_ + d] = (bf16)(o_acc[nt][r] * inv[r]);
        }
    }
}

// ---------------- final LayerNorm on z (f32) -> out f32 ----------------
__global__ __launch_bounds__(256) void k_ln_out(
    const float* __restrict__ z, const float* __restrict__ g,
    const float* __restrict__ bn, float* __restrict__ out)
{
    int row = blockIdx.x;
    int t = threadIdx.x;
    const float* zr = z + (size_t)row * E_;
    float4 v = *(const float4*)(zr + t * 4);
    float s = v.x + v.y + v.z + v.w;
    float ss = v.x * v.x + v.y * v.y + v.z * v.z + v.w * v.w;
#pragma unroll
    for (int off = 32; off; off >>= 1) {
        s  += __shfl_down(s, off);
        ss += __shfl_down(ss, off);
    }
    __shared__ float red[8];
    int wid = t >> 6;
    if ((t & 63) == 0) { red[wid] = s; red[4 + wid] = ss; }
    __syncthreads();
    float stot  = red[0] + red[1] + red[2] + red[3];
    float sstot = red[4] + red[5] + red[6] + red[7];
    float mean = stot * (1.0f / E_);
    float var  = sstot * (1.0f / E_) - mean * mean;
    float rs = rsqrtf(var + 1e-5f);
    float* outr = out + (size_t)row * E_;
    float vv[4] = {v.x, v.y, v.z, v.w};
#pragma unroll
    for (int j = 0; j < 4; ++j) {
        int i = t * 4 + j;
        outr[i] = ((vv[j] - mean) * rs) * g[i] + bn[i];
    }
}

// ---------------- launch ----------------
extern "C" void kernel_launch(void* const* d_in, const int* in_sizes, int n_in,
                              void* d_out, int out_size, void* d_ws, size_t ws_size,
                              hipStream_t stream) {
    const float* x    = (const float*)d_in[0];
    const float* cond = (const float*)d_in[1];
    const float* Wq   = (const float*)d_in[2];
    const float* bq   = (const float*)d_in[3];
    const float* Wv   = (const float*)d_in[4];
    const float* bv   = (const float*)d_in[5];
    const float* Wk   = (const float*)d_in[6];
    const float* bk   = (const float*)d_in[7];
    const float* Wo   = (const float*)d_in[8];
    const float* bo   = (const float*)d_in[9];
    const float* g1   = (const float*)d_in[10];
    const float* bn1  = (const float*)d_in[11];
    const float* g2   = (const float*)d_in[12];
    const float* bn2  = (const float*)d_in[13];
    const float* Wf1  = (const float*)d_in[14];
    const float* bf1  = (const float*)d_in[15];
    const float* Wf2  = (const float*)d_in[16];
    const float* bf2  = (const float*)d_in[17];
    float* out = (float*)d_out;

    char* ws = (char*)d_ws;
    bf16* Wqv_b = (bf16*)(ws + 0);           // 4,526,080
    bf16* Wk_b  = (bf16*)(ws + 4526080);     // -> 21,831,680
    bf16* Wo_b  = (bf16*)(ws + 21831680);    // -> 23,994,880
    bf16* Wf1_b = (bf16*)(ws + 23994880);    // -> 32,383,488
    bf16* Wf2_b = (bf16*)(ws + 32383488);    // -> 40,772,096
    bf16*  xc  = (bf16*)(ws + 40772096);     // -> 57,811,456
    bf16*  ob  = (bf16*)(ws + 57811456);     // -> 74,850,816
    bf16*  vb  = (bf16*)(ws + 74850816);     // vb pre-attn / hb post-attn
    bf16*  hb  = (bf16*)(ws + 74850816);     // -> 91,890,176
    bf16*  qp  = (bf16*)(ws + 91890176);     // -> 117,056,000
    bf16*  kp  = (bf16*)(ws + 117056000);    // -> 142,221,824
    bf16*  vtb = (bf16*)(ws + 142221824);    // -> 163,193,344
    bf16*  ff1 = (bf16*)(ws + 91890176);     // alias over qp/kp/vt
    float* zb  = (float*)(ws + 40772096);    // alias over xc+ob

    k_cvt<<<(1081600 / 4 + 255) / 256, 256, 0, stream>>>(Wq, Wqv_b, 1081600);
    k_cvt<<<(1081600 / 4 + 255) / 256, 256, 0, stream>>>(Wv, Wqv_b + 1081600, 1081600);
    k_cvt<<<(8652800 / 4 + 255) / 256, 256, 0, stream>>>(Wk, Wk_b, 8652800);
    k_cvt<<<(1081600 / 4 + 255) / 256, 256, 0, stream>>>(Wo, Wo_b, 1081600);
    k_cvt<<<(4194304 / 4 + 255) / 256, 256, 0, stream>>>(Wf1, Wf1_b, 4194304);
    k_cvt<<<(4194304 / 4 + 255) / 256, 256, 0, stream>>>(Wf2, Wf2_b, 4194304);

    k_ln_concat<<<M_, 256, 0, stream>>>(x, cond, g1, bn1, xc);

    // zero qp/kp/vt span (pads must be 0)
    k_zero<<<(4456448 + 255) / 256, 256, 0, stream>>>((uint4*)(ws + 91890176), 4456448);

    // fused Q+V
    k_gemm<EP_QV><<<64 * 17, 256, 0, stream>>>(xc, Wqv_b, bq, bv, M_, 2 * D_, D_, D_, D_, 17,
                                               qp, (float*)vb, 0, (const bf16*)vb, 0, nullptr, nullptr);
    k_gemm<EP_K><<<64 * 9, 256, 0, stream>>>(xc, Wk_b, nullptr, nullptr, M_, D_, D_, D_, D_, 9,
                                             kp, nullptr, 0, nullptr, 0, cond, bk);

    k_transpose_v<<<dim3(S_ / 64, 64), 256, 0, stream>>>(vb, vtb);
    k_attn<<<dim3(S_ / 64, 64), 256, 0, stream>>>(qp, kp, vtb, ob);

    k_gemm<EP_O><<<64 * 8, 256, 0, stream>>>(ob, Wo_b, bo, nullptr, M_, E_, D_, D_, D_, 8,
                                             hb, nullptr, E_, xc, D_, nullptr, nullptr);
    k_gemm<EP_FF1><<<64 * 32, 256, 0, stream>>>(hb, Wf1_b, bf1, nullptr, M_, DFF_, E_, E_, E_, 32,
                                                ff1, nullptr, DFF_, nullptr, 0, nullptr, nullptr);
    k_gemm<EP_FF2><<<64 * 8, 256, 0, stream>>>(ff1, Wf2_b, bf2, nullptr, M_, E_, DFF_, DFF_, DFF_, 8,
                                               nullptr, zb, E_, hb, E_, nullptr, nullptr);

    k_ln_out<<<M_, 256, 0, stream>>>(zb, g2, bn2, out);
}